// Round 11
// baseline (280.532 us; speedup 1.0000x reference)
//
#include <hip/hip_runtime.h>
#include <hip/hip_bf16.h>
#include <stdint.h>

// ---------------------------------------------------------------------------
// RG-LRU block: T=8192, D_MODEL=768, D_RNN=1024, KW=4.
// Round 15: dense GEMMs rebuilt for residency (the 10-round invariant:
// small-K GEMM time tracks blocks/CU, not K-loop structure).  gfx950 unified
// VGPR/AGPR budget: R10's gemm was 92+64=156/wave -> 3 waves/SIMD; this
// version targets <=102 total:
//  - BN=64 tiles: acc = 4x2 f32x4 = 32 AGPR only.
//  - A-tile only in LDS (BK=32 dbuf = 16KB, R4-proven swizzle).
//  - B-frags just-in-time global(L2)->reg from frag-major weights (8 VGPR,
//    no reg-dbuf); vmcnt(2) leaves only next-A cp16s in flight.
//  - grid doubles (2048 blocks gemm1/gemm3) -> 4-5 blocks/CU, 16-20 waves.
//  - conv (R8, 68us), scans, prep byte-identical to R10.
// ---------------------------------------------------------------------------

#define T_LEN 8192
#define DM 768
#define DR 1024
#define NC 128   // scan chunks
#define CL 64    // chunk length

typedef __bf16 bf16x8 __attribute__((ext_vector_type(8)));
typedef float  f32x4  __attribute__((ext_vector_type(4)));

#define AS1 __attribute__((address_space(1)))
#define AS3 __attribute__((address_space(3)))

__device__ __forceinline__ void cp16_g2l(const void* g, void* l) {
    __builtin_amdgcn_global_load_lds((const AS1 void*)g, (AS3 void*)l, 16, 0, 0);
}

__device__ __forceinline__ float gelu_tanh(float x) {
    const float inner = 0.7978845608028654f * (x + 0.044715f * x * x * x);
    return 0.5f * x * (1.f + tanhf(inner));
}

__device__ __forceinline__ __bf16 f2b(float v) {
    __hip_bfloat16 h = __float2bfloat16(v);
    return *reinterpret_cast<__bf16*>(&h);
}

// ---------------------------------------------------------------------------
// Dense GEMM, BN=64, residency-first: C[m,n] = sum_k A[m,k]*B[n,k] (+bias).
// BM=128, BK=32, 256 threads (4 waves, 2Mx2N over 128x64), target 4-5
// blocks/CU (acc 32 AGPR + ~60 VGPR).
// A: LDS dbuf [2][128*32]; 32-wide rows = 4 chunks; slot s of row r holds
//    global chunk s ^ ((r>>1)&3) (R4-proven bank-balanced scheme).
// B: fragment-major WF [ntile][kt][lane][16B] (from prep); lane fq*16+frow
//    of frag (nt,kt) holds B[nt*16+frow][kt*32+fq*8..+7].  NI=2 frags
//    loaded just-in-time, 1KB coalesced per wave, straight to regs.
// Per iter t: loadB(t) -> stageA(t+1) -> vmcnt(2) -> barrier ->
//             4 ds_read af + 8 MFMA -> barrier.   K % 32 == 0.
// EPI: 0 = fp32 +bias; 1 = bf16 +bias; 2 = split (gelu->Cv / D2 rows+3).
// Epilogue via swizzled LDS for coalesced 16B stores.
// ---------------------------------------------------------------------------
template<int EPI>
__global__ __launch_bounds__(256, 4)
void gemm_mfma(const __hip_bfloat16* __restrict__ A,
               const __hip_bfloat16* __restrict__ WF,
               const float* __restrict__ bias,
               void* __restrict__ Cv,
               int K, int lda, int N,
               __hip_bfloat16* __restrict__ D2)
{
    __shared__ __align__(16) unsigned char smem[32768];
    __bf16* Asb = (__bf16*)smem;           // [2][128*32] = 16KB

    const int tid  = threadIdx.x;
    const int lane = tid & 63;
    const int wave = tid >> 6;
    const size_t m0 = (size_t)blockIdx.x * 128;
    const int    n0 = blockIdx.y * 64;
    const int wm = (wave >> 1) * 64;
    const int wn = (wave & 1) * 32;

    f32x4 acc[4][2];
#pragma unroll
    for (int i = 0; i < 4; ++i)
#pragma unroll
        for (int j = 0; j < 2; ++j)
            acc[i][j] = f32x4{0.f, 0.f, 0.f, 0.f};

    const int frow = lane & 15;
    const int fq   = lane >> 4;             // chunk index 0..3 in 32-wide row
    const int NKT  = K >> 5;                // 32-col k-steps

    // per-lane base into fragment-major weights: ntile_base = (n0+wn)/16
    const __bf16* wbase = (const __bf16*)WF +
        (((size_t)((n0 + wn) >> 4) * NKT) << 9) + (lane << 3);

    auto stageA = [&](int buf, int k0) {   // 128 rows x 4 chunks = 512 chunks
#pragma unroll
        for (int q = 0; q < 2; ++q) {
            const int lin = q * 256 + tid;
            const int rr  = lin >> 2;
            const int gc  = (lin & 3) ^ ((rr >> 1) & 3);
            cp16_g2l(A + (m0 + rr) * (size_t)lda + k0 + gc * 8,
                     Asb + buf * 4096 + lin * 8);
        }
    };

    stageA(0, 0);
#pragma unroll 1
    for (int t = 0; t < NKT; ++t) {
        bf16x8 bfr[2];
#pragma unroll
        for (int ni = 0; ni < 2; ++ni)
            bfr[ni] = *(const bf16x8*)(wbase +
                (((size_t)(ni * NKT + t)) << 9));
        if (t + 1 < NKT) {
            stageA((t + 1) & 1, (t + 1) * 32);
            // leave only the 2 just-issued next-A cp16s in flight; this
            // iter's A (oldest) and B (middle) must be complete.
            asm volatile("s_waitcnt vmcnt(2)" ::: "memory");
        } else {
            asm volatile("s_waitcnt vmcnt(0)" ::: "memory");
        }
        __builtin_amdgcn_sched_barrier(0);
        __builtin_amdgcn_s_barrier();          // A[t&1] staged for all waves
        __builtin_amdgcn_sched_barrier(0);

        const int ab = (t & 1) * 4096;
        bf16x8 af[4];
#pragma unroll
        for (int mi = 0; mi < 4; ++mi) {
            const int R = wm + mi * 16 + frow;
            af[mi] = *(const bf16x8*)&Asb[ab + R * 32 + ((fq ^ ((R >> 1) & 3)) * 8)];
        }
        asm volatile("s_waitcnt lgkmcnt(0)" ::: "memory");
        __builtin_amdgcn_sched_barrier(0);
        __builtin_amdgcn_s_setprio(1);
#pragma unroll
        for (int mi = 0; mi < 4; ++mi)
#pragma unroll
            for (int ni = 0; ni < 2; ++ni)
                acc[mi][ni] = __builtin_amdgcn_mfma_f32_16x16x32_bf16(
                    af[mi], bfr[ni], acc[mi][ni], 0, 0, 0);
        __builtin_amdgcn_s_setprio(0);
        __builtin_amdgcn_sched_barrier(0);
        __builtin_amdgcn_s_barrier();          // A[t&1] free for overwrite
        __builtin_amdgcn_sched_barrier(0);
    }

    // ---- epilogue: acc -> swizzled LDS -> coalesced 16B/lane global stores.
    // C/D frag layout: col = lane&15, row = (lane>>4)*4 + reg.
    __syncthreads();
    const int er = fq * 4;
    const int ec = frow;

    if (EPI == 0) {
        // fp32 tile 128 x 64: 32 KB = the whole arena (R8-proven path).
        float* Cl = (float*)smem;
#pragma unroll
        for (int ni = 0; ni < 2; ++ni) {
            const int cc = wn + ni * 16 + ec;
            const float bv = bias ? bias[n0 + cc] : 0.f;
#pragma unroll
            for (int mi = 0; mi < 4; ++mi)
#pragma unroll
                for (int r2 = 0; r2 < 4; ++r2) {
                    const int R = wm + mi * 16 + er + r2;
                    Cl[R * 64 + ((((cc >> 2) ^ (R & 7)) << 2) | (cc & 3))] =
                        acc[mi][ni][r2] + bv;
                }
        }
        __syncthreads();
        float* outp = (float*)Cv;
#pragma unroll
        for (int p = 0; p < 8; ++p) {
            const int R   = (tid >> 4) + p * 16;
            const int chn = tid & 15;
            const f32x4 v = *(const f32x4*)&Cl[R * 64 + ((chn ^ (R & 7)) << 2)];
            *(f32x4*)&outp[(m0 + R) * (size_t)N + n0 + chn * 4] = v;
        }
    } else {
        // bf16 tile 128 x 64 = 16 KB.
        __bf16* Cl = (__bf16*)smem;
        const bool ahalf = (EPI == 2) && (n0 < 1024);   // block-uniform
#pragma unroll
        for (int ni = 0; ni < 2; ++ni) {
            const int cc = wn + ni * 16 + ec;
            const float bv = bias ? bias[n0 + cc] : 0.f;
#pragma unroll
            for (int mi = 0; mi < 4; ++mi)
#pragma unroll
                for (int r2 = 0; r2 < 4; ++r2) {
                    const int R = wm + mi * 16 + er + r2;
                    float v = acc[mi][ni][r2] + bv;
                    if (EPI == 2 && ahalf) v = gelu_tanh(v);
                    Cl[R * 64 + ((((cc >> 3) ^ (R & 7)) << 3) | (cc & 7))] = f2b(v);
                }
        }
        __syncthreads();
#pragma unroll
        for (int p = 0; p < 4; ++p) {
            const int R   = (tid >> 3) + p * 32;
            const int chn = tid & 7;
            const bf16x8 v = *(const bf16x8*)&Cl[R * 64 + ((chn ^ (R & 7)) << 3)];
            if (EPI == 1) {
                *(bf16x8*)((__bf16*)Cv + (m0 + R) * (size_t)N + n0 + chn * 8) = v;
            } else if (n0 < 1024) {
                *(bf16x8*)((__bf16*)Cv + (m0 + R) * 1024 + n0 + chn * 8) = v;
            } else {
                *(bf16x8*)((__bf16*)D2 + (m0 + R + 3) * 1024 + (n0 - 1024) + chn * 8) = v;
            }
        }
    }
}

// ---------------------------------------------------------------------------
// Conv (byte-identical to R8): B-frags global->register, A-halo LDS dbuf,
// 64 MFMA/wave per barrier-pair, 2 blocks/CU.
// ---------------------------------------------------------------------------
__global__ __launch_bounds__(256, 2)
void conv_mfma(const __hip_bfloat16* __restrict__ bbp,
               const __hip_bfloat16* __restrict__ WB,
               __hip_bfloat16* __restrict__ C)
{
    __shared__ __align__(16) unsigned char smem[32768];
    __bf16* Ah = (__bf16*)smem;             // [2][132*32] halo dbuf (16.9KB)

    const int tid  = threadIdx.x;
    const int lane = tid & 63;
    const int wave = tid >> 6;
    const size_t m0 = (size_t)blockIdx.x * 128;
    const int    n0 = blockIdx.y * 128;
    const int wm = (wave >> 1) * 64;
    const int wn = (wave & 1) * 64;

    f32x4 acc[4][4];
#pragma unroll
    for (int i = 0; i < 4; ++i)
#pragma unroll
        for (int j = 0; j < 4; ++j)
            acc[i][j] = f32x4{0.f, 0.f, 0.f, 0.f};

    const int frow = lane & 15;
    const int fq   = lane >> 4;

    const __bf16* wbase = (const __bf16*)WB +
        ((size_t)((n0 + wn) >> 4) << 16) + (lane << 3);

    auto loadB = [&](bf16x8 (&b)[4][4], int t1) {
#pragma unroll
        for (int s = 0; s < 4; ++s)
#pragma unroll
            for (int ni = 0; ni < 4; ++ni)
                b[s][ni] = *(const bf16x8*)(wbase + ((size_t)ni << 16) +
                                            t1 * 2048 + s * 512);
    };
    auto stageA = [&](int abuf, int kc) {   // 132 rows x 4 chunks = 528 chunks
#pragma unroll
        for (int q = 0; q < 2; ++q) {
            const int lin = q * 256 + tid;
            const int rr  = lin >> 2;
            const int gc  = (lin & 3) ^ ((rr >> 1) & 3);
            cp16_g2l(bbp + (m0 + rr) * 1024 + kc + gc * 8, Ah + abuf * 4224 + lin * 8);
        }
        if (tid < 16) {
            const int lin = 512 + tid;
            const int rr  = lin >> 2;
            const int gc  = (lin & 3) ^ ((rr >> 1) & 3);
            cp16_g2l(bbp + (m0 + rr) * 1024 + kc + gc * 8, Ah + abuf * 4224 + lin * 8);
        }
    };

    bf16x8 bA[4][4], bB[4][4];
    stageA(0, 0);
    loadB(bA, 0);

    auto iter = [&](bf16x8 (&bCur)[4][4], bf16x8 (&bNxt)[4][4], int t) {
        if (t + 1 < 32) {
            loadB(bNxt, t + 1);
            asm volatile("s_waitcnt vmcnt(16)" ::: "memory");
        } else {
            asm volatile("s_waitcnt vmcnt(0)" ::: "memory");
        }
        __builtin_amdgcn_sched_barrier(0);
        __builtin_amdgcn_s_barrier();          // halo[t&1] staged for all waves
        __builtin_amdgcn_sched_barrier(0);

        const int ab = (t & 1) * 4224;
        __builtin_amdgcn_s_setprio(1);
#pragma unroll
        for (int s = 0; s < 4; ++s) {
            bf16x8 af[4];
#pragma unroll
            for (int mi = 0; mi < 4; ++mi) {
                const int R = wm + mi * 16 + frow + s;       // shifted halo row
                af[mi] = *(const bf16x8*)&Ah[ab + R * 32 + ((fq ^ ((R >> 1) & 3)) * 8)];
            }
#pragma unroll
            for (int mi = 0; mi < 4; ++mi)
#pragma unroll
                for (int ni = 0; ni < 4; ++ni)
                    acc[mi][ni] = __builtin_amdgcn_mfma_f32_16x16x32_bf16(
                        af[mi], bCur[s][ni], acc[mi][ni], 0, 0, 0);
        }
        __builtin_amdgcn_s_setprio(0);
        __builtin_amdgcn_sched_barrier(0);
        __builtin_amdgcn_s_barrier();          // halo[t&1] free for overwrite
        __builtin_amdgcn_sched_barrier(0);
        if (t + 1 < 32) stageA((t + 1) & 1, (t + 1) * 32);
    };

#pragma unroll 1
    for (int tp = 0; tp < 16; ++tp) {
        iter(bA, bB, 2 * tp);
        iter(bB, bA, 2 * tp + 1);
    }

    // ---- epilogue: bf16 tile 128x128 via swizzled LDS, coalesced stores.
    __syncthreads();
    const int er = fq * 4;
    const int ec = frow;
    __bf16* Cl = (__bf16*)smem;
#pragma unroll
    for (int ni = 0; ni < 4; ++ni) {
        const int cc = wn + ni * 16 + ec;
#pragma unroll
        for (int mi = 0; mi < 4; ++mi)
#pragma unroll
            for (int r2 = 0; r2 < 4; ++r2) {
                const int R = wm + mi * 16 + er + r2;
                Cl[R * 128 + ((((cc >> 3) ^ (R & 7)) << 3) | (cc & 7))] =
                    f2b(acc[mi][ni][r2]);
            }
    }
    __syncthreads();
#pragma unroll
    for (int p = 0; p < 8; ++p) {
        const int R   = (tid >> 4) + p * 16;
        const int chn = tid & 15;
        const bf16x8 v = *(const bf16x8*)&Cl[R * 128 + ((chn ^ (R & 7)) << 3)];
        *(bf16x8*)((__bf16*)C + (m0 + R) * 1024 + n0 + chn * 8) = v;
    }
}

// One prep kernel (byte-identical to R10).  w1/w_rg/w_out in FRAGMENT-MAJOR
// [ntile][kt][lane][8]: lane(fq*16+frow) of frag (nt,kt) holds
// W[nt*16+frow][kt*32+fq*8+j0].  conv WB layout + bbp pad unchanged.
#define PREP_X   6291456            // 8192*768
#define PREP_W1  (PREP_X + 1572864) // + 2048*768
#define PREP_WRG (PREP_W1 + 2097152)// + 2048*1024
#define PREP_WO  (PREP_WRG + 786432)// + 768*1024
#define PREP_CW  (PREP_WO + 4194304)// + 1024*4096
#define PREP_TOT (PREP_CW + 3072)   // + pad rows
__global__ void prep_kernel(const float* __restrict__ x, const float* __restrict__ w1,
                            const float* __restrict__ w_rg, const float* __restrict__ w_out,
                            const float* __restrict__ conv_w,
                            __hip_bfloat16* __restrict__ xb, __hip_bfloat16* __restrict__ w1f,
                            __hip_bfloat16* __restrict__ w_rgf, __hip_bfloat16* __restrict__ w_outf,
                            __hip_bfloat16* __restrict__ wbigb, __hip_bfloat16* __restrict__ bbp)
{
    const int idx = blockIdx.x * 256 + threadIdx.x;
    if (idx < PREP_X) {
        xb[idx] = __float2bfloat16(x[idx]);
    } else if (idx < PREP_W1) {
        // w1f: K=768, NKT=24, ntile block = 24*512 = 12288 elements
        const int i  = idx - PREP_X;
        const int nti = i / 12288;
        const int r  = i % 12288;
        const int kt = r >> 9;
        const int r2 = r & 511;
        const int l  = r2 >> 3, j0 = r2 & 7;
        const int row = nti * 16 + (l & 15);
        const int col = kt * 32 + (l >> 4) * 8 + j0;
        w1f[i] = __float2bfloat16(w1[row * 768 + col]);
    } else if (idx < PREP_WRG) {
        // w_rgf: K=1024, NKT=32, ntile block = 16384 elements
        const int i  = idx - PREP_W1;
        const int nti = i >> 14;
        const int r  = i & 16383;
        const int kt = r >> 9;
        const int r2 = r & 511;
        const int l  = r2 >> 3, j0 = r2 & 7;
        const int row = nti * 16 + (l & 15);
        const int col = kt * 32 + (l >> 4) * 8 + j0;
        w_rgf[i] = __float2bfloat16(w_rg[row * 1024 + col]);
    } else if (idx < PREP_WO) {
        // w_outf: 768 rows, K=1024, NKT=32
        const int i  = idx - PREP_WRG;
        const int nti = i >> 14;
        const int r  = i & 16383;
        const int kt = r >> 9;
        const int r2 = r & 511;
        const int l  = r2 >> 3, j0 = r2 & 7;
        const int row = nti * 16 + (l & 15);
        const int col = kt * 32 + (l >> 4) * 8 + j0;
        w_outf[i] = __float2bfloat16(w_out[row * 1024 + col]);
    } else if (idx < PREP_CW) {
        // fragment-major conv weights: WB[nt][kcI][s][lane][8 bf16]
        const int n    = idx - PREP_WO;
        const int nti  = n >> 16;
        const int r1   = n & 65535;
        const int kcI  = r1 >> 11;
        const int r2   = r1 & 2047;
        const int s    = r2 >> 9;
        const int r3   = r2 & 511;
        const int l    = r3 >> 3;
        const int j0   = r3 & 7;
        const int frow = l & 15, fq = l >> 4;
        const int o = nti * 16 + frow;
        const int i = kcI * 32 + fq * 8 + j0;
        wbigb[n] = __float2bfloat16(conv_w[o * 4096 + i * 4 + s]);
    } else {
        bbp[idx - PREP_CW] = __float2bfloat16(0.f);
    }
}

// Gates recomputed inline from g_pre (T x 2048 bf16) + bc (bf16):
__global__ void scan_pass1(const __hip_bfloat16* __restrict__ gp,
                           const __hip_bfloat16* __restrict__ bc,
                           const float* __restrict__ Lambda,
                           float* __restrict__ ch, float* __restrict__ ca)
{
    const int c = blockIdx.y * 256 + threadIdx.x;
    const int j = blockIdx.x;
    const float cl = -8.f * log1pf(expf(Lambda[c]));
    float h = 0.f, ap = 1.f;
    const int t0 = j * CL;
    for (int tt = 0; tt < CL; ++tt) {
        const int t = t0 + tt;
        const long gi = (long)t * 2048 + c;
        const float ig = 1.f / (1.f + expf(-__bfloat162float(gp[gi])));
        const float rg = 1.f / (1.f + expf(-__bfloat162float(gp[gi + 1024])));
        const float a  = expf(cl * rg);
        const float gx = sqrtf(fmaxf(0.f, 1.f - a * a)) * ig *
                         __bfloat162float(bc[(long)t * 1024 + c]);
        h  = fmaf(a, h, gx);
        ap *= a;
    }
    ch[j * 1024 + c] = h;
    ca[j * 1024 + c] = ap;
}

__global__ void scan_combine(float* __restrict__ ch, const float* __restrict__ ca)
{
    const int c = blockIdx.x * 256 + threadIdx.x;
    float carry = 0.f;
    for (int j = 0; j < NC; ++j) {
        const float hj = ch[j * 1024 + c];
        const float aj = ca[j * 1024 + c];
        ch[j * 1024 + c] = carry;
        carry = fmaf(aj, carry, hj);
    }
}

// Rescan with carry; z = ab * y -> bf16 (zb aliases bc: same-element RMW per thread).
__global__ void scan_pass2(const __hip_bfloat16* __restrict__ gp, const __hip_bfloat16* bc,
                           const float* __restrict__ Lambda,
                           const float* __restrict__ carry_in,
                           const __hip_bfloat16* __restrict__ ab,
                           __hip_bfloat16* zb)
{
    const int c = blockIdx.y * 256 + threadIdx.x;
    const int j = blockIdx.x;
    const float cl = -8.f * log1pf(expf(Lambda[c]));
    float h = carry_in[j * 1024 + c];
    const int t0 = j * CL;
    for (int tt = 0; tt < CL; ++tt) {
        const int t = t0 + tt;
        const long gi = (long)t * 2048 + c;
        const long bi = (long)t * 1024 + c;
        const float ig = 1.f / (1.f + expf(-__bfloat162float(gp[gi])));
        const float rg = 1.f / (1.f + expf(-__bfloat162float(gp[gi + 1024])));
        const float a  = expf(cl * rg);
        const float gx = sqrtf(fmaxf(0.f, 1.f - a * a)) * ig * __bfloat162float(bc[bi]);
        h = fmaf(a, h, gx);
        zb[bi] = __float2bfloat16(__bfloat162float(ab[bi]) * h);
    }
}

extern "C" void kernel_launch(void* const* d_in, const int* in_sizes, int n_in,
                              void* d_out, int out_size, void* d_ws, size_t ws_size,
                              hipStream_t stream)
{
    const float* x      = (const float*)d_in[0];
    const float* w1     = (const float*)d_in[1];
    const float* b1     = (const float*)d_in[2];
    const float* conv_w = (const float*)d_in[3];
    const float* w_rg   = (const float*)d_in[4];
    const float* b_rg   = (const float*)d_in[5];
    const float* w_out  = (const float*)d_in[6];
    const float* b_out  = (const float*)d_in[7];
    const float* Lambda = (const float*)d_in[8];
    float* out = (float*)d_out;
    (void)in_sizes; (void)n_in; (void)out_size; (void)ws_size;

    // ---- workspace layout (~110 MB) ----
    char* p = (char*)d_ws;
    auto alloc = [&](size_t bytes) { char* r = p; p += (bytes + 255) & ~255ULL; return r; };
    __hip_bfloat16* gpre  = (__hip_bfloat16*)alloc(8192ULL * 2048 * 2); // 32 MB
    __hip_bfloat16* ab    = (__hip_bfloat16*)alloc(8192ULL * 1024 * 2); // 16 MB
    __hip_bfloat16* bbp   = (__hip_bfloat16*)alloc(8200ULL * 1024 * 2); // 16.8 MB
    __hip_bfloat16* bcb   = (__hip_bfloat16*)alloc(8192ULL * 1024 * 2); // 16 MB (later zb)
    __hip_bfloat16* wbigb = (__hip_bfloat16*)alloc(1024ULL * 4096 * 2); // 8 MB
    __hip_bfloat16* xb    = (__hip_bfloat16*)alloc(8192ULL * 768 * 2);  // 12 MB
    __hip_bfloat16* w1f   = (__hip_bfloat16*)alloc(2048ULL * 768 * 2);  // 3 MB (frag-major)
    __hip_bfloat16* w_rgf = (__hip_bfloat16*)alloc(2048ULL * 1024 * 2); // 4 MB (frag-major)
    __hip_bfloat16* w_outf= (__hip_bfloat16*)alloc(768ULL * 1024 * 2);  // 1.5 MB (frag-major)
    float*          chv   = (float*)alloc(NC * 1024ULL * 4);
    float*          cav   = (float*)alloc(NC * 1024ULL * 4);
    __hip_bfloat16* zb    = bcb;   // overlay

    prep_kernel<<<PREP_TOT / 256, 256, 0, stream>>>(x, w1, w_rg, w_out, conv_w,
                                                    xb, w1f, w_rgf, w_outf, wbigb, bbp);

    // h = x @ w1.T + b1, fused split: ab = bf16(gelu), bbp = bf16 (rows +3)
    {
        dim3 grid(T_LEN / 128, 2048 / 64);
        gemm_mfma<2><<<grid, 256, 0, stream>>>(xb, w1f, b1, ab, DM, DM, 2048, bbp);
    }

    // bc = causal conv (B-frags global->reg from fragment-major WB) -> bf16
    {
        dim3 grid(T_LEN / 128, 1024 / 128);
        conv_mfma<<<grid, 256, 0, stream>>>(bbp, wbigb, bcb);
    }

    // g_pre = bc @ w_rg.T + b_rg -> bf16
    {
        dim3 grid(T_LEN / 128, 2048 / 64);
        gemm_mfma<1><<<grid, 256, 0, stream>>>(bcb, w_rgf, b_rg, gpre, DR, DR, 2048, nullptr);
    }

    // chunked scan with fused gates; z = ab*y -> bf16 (overlays bcb)
    {
        dim3 gs(NC, DR / 256);
        scan_pass1<<<gs, 256, 0, stream>>>(gpre, bcb, Lambda, chv, cav);
        scan_combine<<<DR / 256, 256, 0, stream>>>(chv, cav);
        scan_pass2<<<gs, 256, 0, stream>>>(gpre, bcb, Lambda, chv, ab, zb);
    }

    // out = z @ w_out.T + b_out -> fp32
    {
        dim3 grid(T_LEN / 128, DM / 64);
        gemm_mfma<0><<<grid, 256, 0, stream>>>(zb, w_outf, b_out, out, DR, DR, DM, nullptr);
    }
}

// Round 12
// 278.009 us; speedup vs baseline: 1.0091x; 1.0091x over previous
//
#include <hip/hip_runtime.h>
#include <hip/hip_bf16.h>
#include <stdint.h>

// ---------------------------------------------------------------------------
// RG-LRU block: T=8192, D_MODEL=768, D_RNN=1024, KW=4.
// Round 16: dense-GEMM ring-4 / depth-2 / single-barrier.  R11 evidence:
// gemm iters are ~600 cyc work + ~2800 cyc wait (Mfma 15%, VALU 27%, HBM 11%,
// occ 41% -- nothing saturated).  1-deep dbuf only covers one (deflated)
// iteration of latency.  This round:
//  - A tiles in a 4-slot LDS ring (4x8KB), staged 2 iters ahead.
//  - FIFO-counted vmcnt: issue B(t+1) then A(t+2); steady wait vmcnt(6)
//    retires exactly A(t)+B(t); tails 4/0 (induction-verified).
//  - ONE s_barrier per iter (ring distance 3 write-slot vs slowest reader).
//  - conv (R8), scans, prep byte-identical to R11.
// ---------------------------------------------------------------------------

#define T_LEN 8192
#define DM 768
#define DR 1024
#define NC 128   // scan chunks
#define CL 64    // chunk length

typedef __bf16 bf16x8 __attribute__((ext_vector_type(8)));
typedef float  f32x4  __attribute__((ext_vector_type(4)));

#define AS1 __attribute__((address_space(1)))
#define AS3 __attribute__((address_space(3)))

__device__ __forceinline__ void cp16_g2l(const void* g, void* l) {
    __builtin_amdgcn_global_load_lds((const AS1 void*)g, (AS3 void*)l, 16, 0, 0);
}

__device__ __forceinline__ float gelu_tanh(float x) {
    const float inner = 0.7978845608028654f * (x + 0.044715f * x * x * x);
    return 0.5f * x * (1.f + tanhf(inner));
}

__device__ __forceinline__ __bf16 f2b(float v) {
    __hip_bfloat16 h = __float2bfloat16(v);
    return *reinterpret_cast<__bf16*>(&h);
}

// ---------------------------------------------------------------------------
// Dense GEMM, BN=64, ring-4 depth-2: C[m,n] = sum_k A[m,k]*B[n,k] (+bias).
// BM=128, BK=32, 256 threads (4 waves, 2Mx2N over 128x64), 4 blocks/CU
// (acc 32 AGPR + ~46 VGPR).
// A: LDS ring [4][128*32] (8KB/slot); 32-wide rows = 4 chunks; slot s of
//    row r holds global chunk s ^ ((r>>1)&3) (R4-proven scheme).
// B: fragment-major WF [ntile][kt][lane][16B]; NI=2 frags, reg ping-pong,
//    prefetched 1 iter ahead.
// Per iter t: loadB(t+1) -> stageA(t+2 into slot (t+2)&3) -> counted vmcnt
//   (6 steady / 4 / 0 tail) -> ONE barrier -> 4 ds_read + 8 MFMA.
// Safety: fastest wave is <=1 barrier ahead of slowest; writer slot (t+2)&3
// vs slowest reader slot (t-1)&3 differ by 3 mod 4 -> no overwrite race.
// EPI: 0 = fp32 +bias; 1 = bf16 +bias; 2 = split (gelu->Cv / D2 rows+3).
// ---------------------------------------------------------------------------
template<int EPI>
__global__ __launch_bounds__(256, 4)
void gemm_mfma(const __hip_bfloat16* __restrict__ A,
               const __hip_bfloat16* __restrict__ WF,
               const float* __restrict__ bias,
               void* __restrict__ Cv,
               int K, int lda, int N,
               __hip_bfloat16* __restrict__ D2)
{
    __shared__ __align__(16) unsigned char smem[32768];
    __bf16* Asb = (__bf16*)smem;           // [4][128*32] ring, 8KB/slot

    const int tid  = threadIdx.x;
    const int lane = tid & 63;
    const int wave = tid >> 6;
    const size_t m0 = (size_t)blockIdx.x * 128;
    const int    n0 = blockIdx.y * 64;
    const int wm = (wave >> 1) * 64;
    const int wn = (wave & 1) * 32;

    f32x4 acc[4][2];
#pragma unroll
    for (int i = 0; i < 4; ++i)
#pragma unroll
        for (int j = 0; j < 2; ++j)
            acc[i][j] = f32x4{0.f, 0.f, 0.f, 0.f};

    const int frow = lane & 15;
    const int fq   = lane >> 4;             // chunk index 0..3 in 32-wide row
    const int NKT  = K >> 5;                // 32-col k-steps

    // per-lane base into fragment-major weights: ntile_base = (n0+wn)/16
    const __bf16* wbase = (const __bf16*)WF +
        (((size_t)((n0 + wn) >> 4) * NKT) << 9) + (lane << 3);

    auto loadB = [&](bf16x8 (&b)[2], int t1) {
#pragma unroll
        for (int ni = 0; ni < 2; ++ni)
            b[ni] = *(const bf16x8*)(wbase +
                (((size_t)(ni * NKT + t1)) << 9));
    };
    auto stageA = [&](int slot, int k0) {  // 128 rows x 4 chunks = 512 chunks
#pragma unroll
        for (int q = 0; q < 2; ++q) {
            const int lin = q * 256 + tid;
            const int rr  = lin >> 2;
            const int gc  = (lin & 3) ^ ((rr >> 1) & 3);
            cp16_g2l(A + (m0 + rr) * (size_t)lda + k0 + gc * 8,
                     Asb + slot * 4096 + lin * 8);
        }
    };

    bf16x8 bA[2], bB[2];
    // prologue issue order (FIFO): A(0), B(0), A(1)
    stageA(0, 0);
    loadB(bA, 0);
    stageA(1, 32);

    auto iter = [&](bf16x8 (&bCur)[2], bf16x8 (&bNxt)[2], int t) {
        if (t + 1 < NKT) loadB(bNxt, t + 1);
        if (t + 2 < NKT) stageA((t + 2) & 3, (t + 2) * 32);
        // retire exactly A(t)+B(t); keep {A(t+1),B(t+1),A(t+2)} in flight
        if (t + 2 < NKT)      asm volatile("s_waitcnt vmcnt(6)" ::: "memory");
        else if (t + 1 < NKT) asm volatile("s_waitcnt vmcnt(4)" ::: "memory");
        else                  asm volatile("s_waitcnt vmcnt(0)" ::: "memory");
        __builtin_amdgcn_sched_barrier(0);
        __builtin_amdgcn_s_barrier();          // A[t&3] staged for all waves
        __builtin_amdgcn_sched_barrier(0);

        const int ab = (t & 3) * 4096;
        bf16x8 af[4];
#pragma unroll
        for (int mi = 0; mi < 4; ++mi) {
            const int R = wm + mi * 16 + frow;
            af[mi] = *(const bf16x8*)&Asb[ab + R * 32 + ((fq ^ ((R >> 1) & 3)) * 8)];
        }
        asm volatile("s_waitcnt lgkmcnt(0)" ::: "memory");
        __builtin_amdgcn_sched_barrier(0);
        __builtin_amdgcn_s_setprio(1);
#pragma unroll
        for (int mi = 0; mi < 4; ++mi)
#pragma unroll
            for (int ni = 0; ni < 2; ++ni)
                acc[mi][ni] = __builtin_amdgcn_mfma_f32_16x16x32_bf16(
                    af[mi], bCur[ni], acc[mi][ni], 0, 0, 0);
        __builtin_amdgcn_s_setprio(0);
        __builtin_amdgcn_sched_barrier(0);
        // no trailing barrier: ring distance covers slot reuse
    };

#pragma unroll 1
    for (int tp = 0; tp < NKT / 2; ++tp) {
        iter(bA, bB, 2 * tp);
        iter(bB, bA, 2 * tp + 1);
    }

    // ---- epilogue: acc -> swizzled LDS -> coalesced 16B/lane global stores.
    // C/D frag layout: col = lane&15, row = (lane>>4)*4 + reg.
    __syncthreads();
    const int er = fq * 4;
    const int ec = frow;

    if (EPI == 0) {
        // fp32 tile 128 x 64: 32 KB = the whole arena.
        float* Cl = (float*)smem;
#pragma unroll
        for (int ni = 0; ni < 2; ++ni) {
            const int cc = wn + ni * 16 + ec;
            const float bv = bias ? bias[n0 + cc] : 0.f;
#pragma unroll
            for (int mi = 0; mi < 4; ++mi)
#pragma unroll
                for (int r2 = 0; r2 < 4; ++r2) {
                    const int R = wm + mi * 16 + er + r2;
                    Cl[R * 64 + ((((cc >> 2) ^ (R & 7)) << 2) | (cc & 3))] =
                        acc[mi][ni][r2] + bv;
                }
        }
        __syncthreads();
        float* outp = (float*)Cv;
#pragma unroll
        for (int p = 0; p < 8; ++p) {
            const int R   = (tid >> 4) + p * 16;
            const int chn = tid & 15;
            const f32x4 v = *(const f32x4*)&Cl[R * 64 + ((chn ^ (R & 7)) << 2)];
            *(f32x4*)&outp[(m0 + R) * (size_t)N + n0 + chn * 4] = v;
        }
    } else {
        // bf16 tile 128 x 64 = 16 KB.
        __bf16* Cl = (__bf16*)smem;
        const bool ahalf = (EPI == 2) && (n0 < 1024);   // block-uniform
#pragma unroll
        for (int ni = 0; ni < 2; ++ni) {
            const int cc = wn + ni * 16 + ec;
            const float bv = bias ? bias[n0 + cc] : 0.f;
#pragma unroll
            for (int mi = 0; mi < 4; ++mi)
#pragma unroll
                for (int r2 = 0; r2 < 4; ++r2) {
                    const int R = wm + mi * 16 + er + r2;
                    float v = acc[mi][ni][r2] + bv;
                    if (EPI == 2 && ahalf) v = gelu_tanh(v);
                    Cl[R * 64 + ((((cc >> 3) ^ (R & 7)) << 3) | (cc & 7))] = f2b(v);
                }
        }
        __syncthreads();
#pragma unroll
        for (int p = 0; p < 4; ++p) {
            const int R   = (tid >> 3) + p * 32;
            const int chn = tid & 7;
            const bf16x8 v = *(const bf16x8*)&Cl[R * 64 + ((chn ^ (R & 7)) << 3)];
            if (EPI == 1) {
                *(bf16x8*)((__bf16*)Cv + (m0 + R) * (size_t)N + n0 + chn * 8) = v;
            } else if (n0 < 1024) {
                *(bf16x8*)((__bf16*)Cv + (m0 + R) * 1024 + n0 + chn * 8) = v;
            } else {
                *(bf16x8*)((__bf16*)D2 + (m0 + R + 3) * 1024 + (n0 - 1024) + chn * 8) = v;
            }
        }
    }
}

// ---------------------------------------------------------------------------
// Conv (byte-identical to R8): B-frags global->register, A-halo LDS dbuf,
// 64 MFMA/wave per barrier-pair, 2 blocks/CU.
// ---------------------------------------------------------------------------
__global__ __launch_bounds__(256, 2)
void conv_mfma(const __hip_bfloat16* __restrict__ bbp,
               const __hip_bfloat16* __restrict__ WB,
               __hip_bfloat16* __restrict__ C)
{
    __shared__ __align__(16) unsigned char smem[32768];
    __bf16* Ah = (__bf16*)smem;             // [2][132*32] halo dbuf (16.9KB)

    const int tid  = threadIdx.x;
    const int lane = tid & 63;
    const int wave = tid >> 6;
    const size_t m0 = (size_t)blockIdx.x * 128;
    const int    n0 = blockIdx.y * 128;
    const int wm = (wave >> 1) * 64;
    const int wn = (wave & 1) * 64;

    f32x4 acc[4][4];
#pragma unroll
    for (int i = 0; i < 4; ++i)
#pragma unroll
        for (int j = 0; j < 4; ++j)
            acc[i][j] = f32x4{0.f, 0.f, 0.f, 0.f};

    const int frow = lane & 15;
    const int fq   = lane >> 4;

    const __bf16* wbase = (const __bf16*)WB +
        ((size_t)((n0 + wn) >> 4) << 16) + (lane << 3);

    auto loadB = [&](bf16x8 (&b)[4][4], int t1) {
#pragma unroll
        for (int s = 0; s < 4; ++s)
#pragma unroll
            for (int ni = 0; ni < 4; ++ni)
                b[s][ni] = *(const bf16x8*)(wbase + ((size_t)ni << 16) +
                                            t1 * 2048 + s * 512);
    };
    auto stageA = [&](int abuf, int kc) {   // 132 rows x 4 chunks = 528 chunks
#pragma unroll
        for (int q = 0; q < 2; ++q) {
            const int lin = q * 256 + tid;
            const int rr  = lin >> 2;
            const int gc  = (lin & 3) ^ ((rr >> 1) & 3);
            cp16_g2l(bbp + (m0 + rr) * 1024 + kc + gc * 8, Ah + abuf * 4224 + lin * 8);
        }
        if (tid < 16) {
            const int lin = 512 + tid;
            const int rr  = lin >> 2;
            const int gc  = (lin & 3) ^ ((rr >> 1) & 3);
            cp16_g2l(bbp + (m0 + rr) * 1024 + kc + gc * 8, Ah + abuf * 4224 + lin * 8);
        }
    };

    bf16x8 bA[4][4], bB[4][4];
    stageA(0, 0);
    loadB(bA, 0);

    auto iter = [&](bf16x8 (&bCur)[4][4], bf16x8 (&bNxt)[4][4], int t) {
        if (t + 1 < 32) {
            loadB(bNxt, t + 1);
            asm volatile("s_waitcnt vmcnt(16)" ::: "memory");
        } else {
            asm volatile("s_waitcnt vmcnt(0)" ::: "memory");
        }
        __builtin_amdgcn_sched_barrier(0);
        __builtin_amdgcn_s_barrier();          // halo[t&1] staged for all waves
        __builtin_amdgcn_sched_barrier(0);

        const int ab = (t & 1) * 4224;
        __builtin_amdgcn_s_setprio(1);
#pragma unroll
        for (int s = 0; s < 4; ++s) {
            bf16x8 af[4];
#pragma unroll
            for (int mi = 0; mi < 4; ++mi) {
                const int R = wm + mi * 16 + frow + s;       // shifted halo row
                af[mi] = *(const bf16x8*)&Ah[ab + R * 32 + ((fq ^ ((R >> 1) & 3)) * 8)];
            }
#pragma unroll
            for (int mi = 0; mi < 4; ++mi)
#pragma unroll
                for (int ni = 0; ni < 4; ++ni)
                    acc[mi][ni] = __builtin_amdgcn_mfma_f32_16x16x32_bf16(
                        af[mi], bCur[s][ni], acc[mi][ni], 0, 0, 0);
        }
        __builtin_amdgcn_s_setprio(0);
        __builtin_amdgcn_sched_barrier(0);
        __builtin_amdgcn_s_barrier();          // halo[t&1] free for overwrite
        __builtin_amdgcn_sched_barrier(0);
        if (t + 1 < 32) stageA((t + 1) & 1, (t + 1) * 32);
    };

#pragma unroll 1
    for (int tp = 0; tp < 16; ++tp) {
        iter(bA, bB, 2 * tp);
        iter(bB, bA, 2 * tp + 1);
    }

    // ---- epilogue: bf16 tile 128x128 via swizzled LDS, coalesced stores.
    __syncthreads();
    const int er = fq * 4;
    const int ec = frow;
    __bf16* Cl = (__bf16*)smem;
#pragma unroll
    for (int ni = 0; ni < 4; ++ni) {
        const int cc = wn + ni * 16 + ec;
#pragma unroll
        for (int mi = 0; mi < 4; ++mi)
#pragma unroll
            for (int r2 = 0; r2 < 4; ++r2) {
                const int R = wm + mi * 16 + er + r2;
                Cl[R * 128 + ((((cc >> 3) ^ (R & 7)) << 3) | (cc & 7))] =
                    f2b(acc[mi][ni][r2]);
            }
    }
    __syncthreads();
#pragma unroll
    for (int p = 0; p < 8; ++p) {
        const int R   = (tid >> 4) + p * 16;
        const int chn = tid & 15;
        const bf16x8 v = *(const bf16x8*)&Cl[R * 128 + ((chn ^ (R & 7)) << 3)];
        *(bf16x8*)((__bf16*)C + (m0 + R) * 1024 + n0 + chn * 8) = v;
    }
}

// One prep kernel (byte-identical to R11).  w1/w_rg/w_out in FRAGMENT-MAJOR
// [ntile][kt][lane][8]: lane(fq*16+frow) of frag (nt,kt) holds
// W[nt*16+frow][kt*32+fq*8+j0].  conv WB layout + bbp pad unchanged.
#define PREP_X   6291456            // 8192*768
#define PREP_W1  (PREP_X + 1572864) // + 2048*768
#define PREP_WRG (PREP_W1 + 2097152)// + 2048*1024
#define PREP_WO  (PREP_WRG + 786432)// + 768*1024
#define PREP_CW  (PREP_WO + 4194304)// + 1024*4096
#define PREP_TOT (PREP_CW + 3072)   // + pad rows
__global__ void prep_kernel(const float* __restrict__ x, const float* __restrict__ w1,
                            const float* __restrict__ w_rg, const float* __restrict__ w_out,
                            const float* __restrict__ conv_w,
                            __hip_bfloat16* __restrict__ xb, __hip_bfloat16* __restrict__ w1f,
                            __hip_bfloat16* __restrict__ w_rgf, __hip_bfloat16* __restrict__ w_outf,
                            __hip_bfloat16* __restrict__ wbigb, __hip_bfloat16* __restrict__ bbp)
{
    const int idx = blockIdx.x * 256 + threadIdx.x;
    if (idx < PREP_X) {
        xb[idx] = __float2bfloat16(x[idx]);
    } else if (idx < PREP_W1) {
        // w1f: K=768, NKT=24, ntile block = 24*512 = 12288 elements
        const int i  = idx - PREP_X;
        const int nti = i / 12288;
        const int r  = i % 12288;
        const int kt = r >> 9;
        const int r2 = r & 511;
        const int l  = r2 >> 3, j0 = r2 & 7;
        const int row = nti * 16 + (l & 15);
        const int col = kt * 32 + (l >> 4) * 8 + j0;
        w1f[i] = __float2bfloat16(w1[row * 768 + col]);
    } else if (idx < PREP_WRG) {
        // w_rgf: K=1024, NKT=32, ntile block = 16384 elements
        const int i  = idx - PREP_W1;
        const int nti = i >> 14;
        const int r  = i & 16383;
        const int kt = r >> 9;
        const int r2 = r & 511;
        const int l  = r2 >> 3, j0 = r2 & 7;
        const int row = nti * 16 + (l & 15);
        const int col = kt * 32 + (l >> 4) * 8 + j0;
        w_rgf[i] = __float2bfloat16(w_rg[row * 1024 + col]);
    } else if (idx < PREP_WO) {
        // w_outf: 768 rows, K=1024, NKT=32
        const int i  = idx - PREP_WRG;
        const int nti = i >> 14;
        const int r  = i & 16383;
        const int kt = r >> 9;
        const int r2 = r & 511;
        const int l  = r2 >> 3, j0 = r2 & 7;
        const int row = nti * 16 + (l & 15);
        const int col = kt * 32 + (l >> 4) * 8 + j0;
        w_outf[i] = __float2bfloat16(w_out[row * 1024 + col]);
    } else if (idx < PREP_CW) {
        // fragment-major conv weights: WB[nt][kcI][s][lane][8 bf16]
        const int n    = idx - PREP_WO;
        const int nti  = n >> 16;
        const int r1   = n & 65535;
        const int kcI  = r1 >> 11;
        const int r2   = r1 & 2047;
        const int s    = r2 >> 9;
        const int r3   = r2 & 511;
        const int l    = r3 >> 3;
        const int j0   = r3 & 7;
        const int frow = l & 15, fq = l >> 4;
        const int o = nti * 16 + frow;
        const int i = kcI * 32 + fq * 8 + j0;
        wbigb[n] = __float2bfloat16(conv_w[o * 4096 + i * 4 + s]);
    } else {
        bbp[idx - PREP_CW] = __float2bfloat16(0.f);
    }
}

// Gates recomputed inline from g_pre (T x 2048 bf16) + bc (bf16):
__global__ void scan_pass1(const __hip_bfloat16* __restrict__ gp,
                           const __hip_bfloat16* __restrict__ bc,
                           const float* __restrict__ Lambda,
                           float* __restrict__ ch, float* __restrict__ ca)
{
    const int c = blockIdx.y * 256 + threadIdx.x;
    const int j = blockIdx.x;
    const float cl = -8.f * log1pf(expf(Lambda[c]));
    float h = 0.f, ap = 1.f;
    const int t0 = j * CL;
    for (int tt = 0; tt < CL; ++tt) {
        const int t = t0 + tt;
        const long gi = (long)t * 2048 + c;
        const float ig = 1.f / (1.f + expf(-__bfloat162float(gp[gi])));
        const float rg = 1.f / (1.f + expf(-__bfloat162float(gp[gi + 1024])));
        const float a  = expf(cl * rg);
        const float gx = sqrtf(fmaxf(0.f, 1.f - a * a)) * ig *
                         __bfloat162float(bc[(long)t * 1024 + c]);
        h  = fmaf(a, h, gx);
        ap *= a;
    }
    ch[j * 1024 + c] = h;
    ca[j * 1024 + c] = ap;
}

__global__ void scan_combine(float* __restrict__ ch, const float* __restrict__ ca)
{
    const int c = blockIdx.x * 256 + threadIdx.x;
    float carry = 0.f;
    for (int j = 0; j < NC; ++j) {
        const float hj = ch[j * 1024 + c];
        const float aj = ca[j * 1024 + c];
        ch[j * 1024 + c] = carry;
        carry = fmaf(aj, carry, hj);
    }
}

// Rescan with carry; z = ab * y -> bf16 (zb aliases bc: same-element RMW per thread).
__global__ void scan_pass2(const __hip_bfloat16* __restrict__ gp, const __hip_bfloat16* bc,
                           const float* __restrict__ Lambda,
                           const float* __restrict__ carry_in,
                           const __hip_bfloat16* __restrict__ ab,
                           __hip_bfloat16* zb)
{
    const int c = blockIdx.y * 256 + threadIdx.x;
    const int j = blockIdx.x;
    const float cl = -8.f * log1pf(expf(Lambda[c]));
    float h = carry_in[j * 1024 + c];
    const int t0 = j * CL;
    for (int tt = 0; tt < CL; ++tt) {
        const int t = t0 + tt;
        const long gi = (long)t * 2048 + c;
        const long bi = (long)t * 1024 + c;
        const float ig = 1.f / (1.f + expf(-__bfloat162float(gp[gi])));
        const float rg = 1.f / (1.f + expf(-__bfloat162float(gp[gi + 1024])));
        const float a  = expf(cl * rg);
        const float gx = sqrtf(fmaxf(0.f, 1.f - a * a)) * ig * __bfloat162float(bc[bi]);
        h = fmaf(a, h, gx);
        zb[bi] = __float2bfloat16(__bfloat162float(ab[bi]) * h);
    }
}

extern "C" void kernel_launch(void* const* d_in, const int* in_sizes, int n_in,
                              void* d_out, int out_size, void* d_ws, size_t ws_size,
                              hipStream_t stream)
{
    const float* x      = (const float*)d_in[0];
    const float* w1     = (const float*)d_in[1];
    const float* b1     = (const float*)d_in[2];
    const float* conv_w = (const float*)d_in[3];
    const float* w_rg   = (const float*)d_in[4];
    const float* b_rg   = (const float*)d_in[5];
    const float* w_out  = (const float*)d_in[6];
    const float* b_out  = (const float*)d_in[7];
    const float* Lambda = (const float*)d_in[8];
    float* out = (float*)d_out;
    (void)in_sizes; (void)n_in; (void)out_size; (void)ws_size;

    // ---- workspace layout (~110 MB) ----
    char* p = (char*)d_ws;
    auto alloc = [&](size_t bytes) { char* r = p; p += (bytes + 255) & ~255ULL; return r; };
    __hip_bfloat16* gpre  = (__hip_bfloat16*)alloc(8192ULL * 2048 * 2); // 32 MB
    __hip_bfloat16* ab    = (__hip_bfloat16*)alloc(8192ULL * 1024 * 2); // 16 MB
    __hip_bfloat16* bbp   = (__hip_bfloat16*)alloc(8200ULL * 1024 * 2); // 16.8 MB
    __hip_bfloat16* bcb   = (__hip_bfloat16*)alloc(8192ULL * 1024 * 2); // 16 MB (later zb)
    __hip_bfloat16* wbigb = (__hip_bfloat16*)alloc(1024ULL * 4096 * 2); // 8 MB
    __hip_bfloat16* xb    = (__hip_bfloat16*)alloc(8192ULL * 768 * 2);  // 12 MB
    __hip_bfloat16* w1f   = (__hip_bfloat16*)alloc(2048ULL * 768 * 2);  // 3 MB (frag-major)
    __hip_bfloat16* w_rgf = (__hip_bfloat16*)alloc(2048ULL * 1024 * 2); // 4 MB (frag-major)
    __hip_bfloat16* w_outf= (__hip_bfloat16*)alloc(768ULL * 1024 * 2);  // 1.5 MB (frag-major)
    float*          chv   = (float*)alloc(NC * 1024ULL * 4);
    float*          cav   = (float*)alloc(NC * 1024ULL * 4);
    __hip_bfloat16* zb    = bcb;   // overlay

    prep_kernel<<<PREP_TOT / 256, 256, 0, stream>>>(x, w1, w_rg, w_out, conv_w,
                                                    xb, w1f, w_rgf, w_outf, wbigb, bbp);

    // h = x @ w1.T + b1, fused split: ab = bf16(gelu), bbp = bf16 (rows +3)
    {
        dim3 grid(T_LEN / 128, 2048 / 64);
        gemm_mfma<2><<<grid, 256, 0, stream>>>(xb, w1f, b1, ab, DM, DM, 2048, bbp);
    }

    // bc = causal conv (B-frags global->reg from fragment-major WB) -> bf16
    {
        dim3 grid(T_LEN / 128, 1024 / 128);
        conv_mfma<<<grid, 256, 0, stream>>>(bbp, wbigb, bcb);
    }

    // g_pre = bc @ w_rg.T + b_rg -> bf16
    {
        dim3 grid(T_LEN / 128, 2048 / 64);
        gemm_mfma<1><<<grid, 256, 0, stream>>>(bcb, w_rgf, b_rg, gpre, DR, DR, 2048, nullptr);
    }

    // chunked scan with fused gates; z = ab*y -> bf16 (overlays bcb)
    {
        dim3 gs(NC, DR / 256);
        scan_pass1<<<gs, 256, 0, stream>>>(gpre, bcb, Lambda, chv, cav);
        scan_combine<<<DR / 256, 256, 0, stream>>>(chv, cav);
        scan_pass2<<<gs, 256, 0, stream>>>(gpre, bcb, Lambda, chv, ab, zb);
    }

    // out = z @ w_out.T + b_out -> fp32
    {
        dim3 grid(T_LEN / 128, DM / 64);
        gemm_mfma<0><<<grid, 256, 0, stream>>>(zb, w_outf, b_out, out, DR, DR, DM, nullptr);
    }
}